// Round 10
// baseline (234.163 us; speedup 1.0000x reference)
//
#include <hip/hip_runtime.h>

#define D 128            // D_IN == D_OUT == 128
#define NEG_SLOPE 0.01f
#define BSHIFT 7         // 128 dst values per coarse bucket
#define B1 1024          // max coarse buckets (N <= 131072)
#define SCHUNK 4096      // edges per sort block
#define SEPT 16          // edges per thread (SCHUNK / 256)
#define SLOT 2560        // per-bucket slot capacity (mean 2048, sigma 45, max ~2250)

typedef __attribute__((ext_vector_type(8))) short short8;
typedef __attribute__((ext_vector_type(4))) float floatx4;

// bf16 helpers
__device__ __forceinline__ unsigned f2bf_rne(float x) {
    unsigned u = __float_as_uint(x);
    return (u + 0x7fffu + ((u >> 16) & 1u)) >> 16;
}
#define BF_LO(u) __uint_as_float((u) << 16)
#define BF_HI(u) __uint_as_float((u) & 0xffff0000u)

// ---------------- prep: W -> MFMA-fragment-ordered hi/lo bf16 + gcur init ----
__global__ __launch_bounds__(256) void prep_wfrag(const float* __restrict__ W,
                                                  unsigned short* __restrict__ whi,
                                                  unsigned short* __restrict__ wlo,
                                                  int* __restrict__ gcur) {
    if (blockIdx.x == 0) {
        for (int i = threadIdx.x; i < B1; i += 256) gcur[i] = i * SLOT;
    }
    const int idx = blockIdx.x * 256 + threadIdx.x;      // 0..16383
    const int j    = idx & 7;
    const int lane = (idx >> 3) & 63;
    const int tk   = idx >> 9;                           // ct*4+kk
    const int kk = tk & 3, ct = tk >> 2;
    const int k = kk * 32 + (lane >> 4) * 8 + j;
    const int n = ct * 16 + (lane & 15);
    const float x = W[k * D + n];
    const unsigned hi = f2bf_rne(x);
    const float hf = __uint_as_float(hi << 16);
    whi[idx] = (unsigned short)hi;
    wlo[idx] = (unsigned short)(__float_as_uint(x - hf) >> 16);
}

// ---------------- fused: sort_scatter blocks + gemm_zs blocks ----------------
// gemm now uses NO LDS, so fusing no longer costs sort occupancy (round-1's
// failure mode). MFMA-bound gemm blocks and memory/atomic-bound sort blocks
// co-resident on CUs overlap pipes instead of serializing as two dispatches.
__global__ __launch_bounds__(256, 3) void gemm_sort(
        const int* __restrict__ esrc, const int* __restrict__ edst,
        int* __restrict__ gcur, int* __restrict__ pairs, int E, int NSORT,
        const float* __restrict__ h, const unsigned short* __restrict__ whi,
        const unsigned short* __restrict__ wlo, const float* __restrict__ aw,
        unsigned short* __restrict__ z, float* __restrict__ s_src,
        float* __restrict__ s_dst, int N) {
    __shared__ int cnt[B1], exc[B1], gbs[B1], cur[B1];   // 16 KB
    __shared__ int spk[SCHUNK];                          // 16 KB sorted packed pairs
    __shared__ unsigned short sbkt[SCHUNK];              //  8 KB bucket of sorted entry
    __shared__ int wtot[4];                              // per-wave scan totals
    const int t = threadIdx.x;
    const int lane = t & 63;

    if ((int)blockIdx.x < NSORT) {
        // ================= sort body (256 threads, SEPT=16) =================
        const int wv = t >> 6;
#pragma unroll
        for (int k = 0; k < 4; ++k) { cnt[t + k * 256] = 0; cur[t + k * 256] = 0; }
        __syncthreads();

        const int e0 = blockIdx.x * SCHUNK;
        const int n  = min(SCHUNK, E - e0);

        int pk[SEPT], bk[SEPT];
        const int i0 = t * SEPT;
        if (i0 + SEPT - 1 < n) {
#pragma unroll
            for (int v4 = 0; v4 < 4; ++v4) {
                const int4 dv = *(const int4*)&edst[e0 + i0 + v4 * 4];
                const int4 sv = *(const int4*)&esrc[e0 + i0 + v4 * 4];
                const int dd[4] = {dv.x, dv.y, dv.z, dv.w};
                const int ss[4] = {sv.x, sv.y, sv.z, sv.w};
#pragma unroll
                for (int k = 0; k < 4; ++k) {
                    const int kk2 = v4 * 4 + k;
                    bk[kk2] = dd[k] >> BSHIFT;
                    pk[kk2] = (ss[k] << BSHIFT) | (dd[k] & 127);  // 17+7=24 bits
                    atomicAdd(&cnt[bk[kk2]], 1);
                }
            }
        } else {
#pragma unroll
            for (int k = 0; k < SEPT; ++k) {
                const int i = i0 + k;
                if (i < n) {
                    const int d = edst[e0 + i];
                    const int s = esrc[e0 + i];
                    bk[k] = d >> BSHIFT;
                    pk[k] = (s << BSHIFT) | (d & 127);
                    atomicAdd(&cnt[bk[k]], 1);
                } else {
                    bk[k] = -1;
                }
            }
        }
        __syncthreads();

        // exclusive scan over B1 buckets: thread owns 4 buckets, shfl wave scan
        const int b0 = t << 2;
        const int c0 = cnt[b0], c1 = cnt[b0 + 1], c2 = cnt[b0 + 2], c3 = cnt[b0 + 3];
        const int s4 = c0 + c1 + c2 + c3;
        int incl = s4;
#pragma unroll
        for (int o = 1; o < 64; o <<= 1) {
            int v = __shfl_up(incl, o, 64);
            if (lane >= o) incl += v;
        }
        if (lane == 63) wtot[wv] = incl;
        __syncthreads();
        int wpre = 0;
#pragma unroll
        for (int i = 0; i < 4; ++i) wpre += (i < wv) ? wtot[i] : 0;
        const int ex0 = wpre + incl - s4;
        exc[b0]     = ex0;
        exc[b0 + 1] = ex0 + c0;
        exc[b0 + 2] = ex0 + c0 + c1;
        exc[b0 + 3] = ex0 + c0 + c1 + c2;
        // reserve this block's runs (one global atomic per non-empty bucket)
        if (c0) gbs[b0]     = atomicAdd(&gcur[b0], c0);
        if (c1) gbs[b0 + 1] = atomicAdd(&gcur[b0 + 1], c1);
        if (c2) gbs[b0 + 2] = atomicAdd(&gcur[b0 + 2], c2);
        if (c3) gbs[b0 + 3] = atomicAdd(&gcur[b0 + 3], c3);
        __syncthreads();

        // scatter into LDS sorted order
#pragma unroll
        for (int k = 0; k < SEPT; ++k) {
            if (bk[k] >= 0) {
                const int p = exc[bk[k]] + atomicAdd(&cur[bk[k]], 1);
                spk[p]  = pk[k];
                sbkt[p] = (unsigned short)bk[k];
            }
        }
        __syncthreads();

        // linear flush: consecutive i -> mostly same bucket -> contiguous stores
        for (int i = t; i < n; i += 256) {
            const int b = sbkt[i];
            const int pos = gbs[b] + (i - exc[b]);
            if (pos < (b + 1) * SLOT) pairs[pos] = spk[i];
        }
        return;
    }

    // ================= gemm body (round-9 proven, no LDS) =================
    const int gbid = blockIdx.x - NSORT;
    const int quad = lane >> 4, l16 = lane & 15;
    const int rowbase = gbid * 64 + (t >> 6) * 16;
    const int arow = min(rowbase + l16, N - 1);          // clamp: unused C rows unsaved
    const float* __restrict__ hrow = h + (size_t)arow * D;

    // hoist all 8 h loads: independent, all in flight together
    float4 hx[8];
#pragma unroll
    for (int kk = 0; kk < 4; ++kk) {
        const int k0 = kk * 32 + quad * 8;
        hx[kk * 2]     = *(const float4*)&hrow[k0];
        hx[kk * 2 + 1] = *(const float4*)&hrow[k0 + 4];
    }
    union { short8 v; unsigned short u[8]; } ahi[4], alo[4];
#pragma unroll
    for (int kk = 0; kk < 4; ++kk) {
        const float xs[8] = {hx[kk*2].x, hx[kk*2].y, hx[kk*2].z, hx[kk*2].w,
                             hx[kk*2+1].x, hx[kk*2+1].y, hx[kk*2+1].z, hx[kk*2+1].w};
#pragma unroll
        for (int i = 0; i < 8; ++i) {
            const unsigned hi = f2bf_rne(xs[i]);
            const float hf = __uint_as_float(hi << 16);
            ahi[kk].u[i] = (unsigned short)hi;
            alo[kk].u[i] = (unsigned short)(__float_as_uint(xs[i] - hf) >> 16);
        }
    }

    floatx4 acc[8];
#pragma unroll
    for (int ct = 0; ct < 8; ++ct) acc[ct] = (floatx4){0.f, 0.f, 0.f, 0.f};

#pragma unroll
    for (int kk = 0; kk < 4; ++kk)
#pragma unroll
        for (int ct = 0; ct < 8; ++ct) {
            const int fo = ((ct * 4 + kk) * 64 + lane) * 8;   // 16B-aligned
            short8 bhi = *(const short8*)&whi[fo];
            short8 blo = *(const short8*)&wlo[fo];
            acc[ct] = __builtin_amdgcn_mfma_f32_16x16x32_bf16(ahi[kk].v, bhi, acc[ct], 0, 0, 0);
            acc[ct] = __builtin_amdgcn_mfma_f32_16x16x32_bf16(alo[kk].v, bhi, acc[ct], 0, 0, 0);
            acc[ct] = __builtin_amdgcn_mfma_f32_16x16x32_bf16(ahi[kk].v, blo, acc[ct], 0, 0, 0);
        }

    // z store (bf16) from C-frags: elem (row=quad*4+reg, col=ct*16+l16)
#pragma unroll
    for (int ct = 0; ct < 8; ++ct)
#pragma unroll
        for (int reg = 0; reg < 4; ++reg) {
            int r = rowbase + quad * 4 + reg;
            if (r < N)
                z[(size_t)r * D + ct * 16 + l16] = (unsigned short)f2bf_rne(acc[ct][reg]);
        }

    // fused scores: per-lane partials for this lane's 4 rows, reduce across l16
    float ps[4] = {0.f, 0.f, 0.f, 0.f}, pd[4] = {0.f, 0.f, 0.f, 0.f};
#pragma unroll
    for (int ct = 0; ct < 8; ++ct) {
        float as = aw[ct * 16 + l16];
        float ad = aw[128 + ct * 16 + l16];
#pragma unroll
        for (int reg = 0; reg < 4; ++reg) {
            ps[reg] = fmaf(acc[ct][reg], as, ps[reg]);
            pd[reg] = fmaf(acc[ct][reg], ad, pd[reg]);
        }
    }
#pragma unroll
    for (int reg = 0; reg < 4; ++reg)
#pragma unroll
        for (int o = 1; o < 16; o <<= 1) {               // all 64 lanes active
            ps[reg] += __shfl_xor(ps[reg], o, 64);
            pd[reg] += __shfl_xor(pd[reg], o, 64);
        }
    if (l16 == 0) {
#pragma unroll
        for (int reg = 0; reg < 4; ++reg) {
            int r = rowbase + quad * 4 + reg;
            if (r < N) { s_src[r] = ps[reg]; s_dst[r] = pd[reg]; }
        }
    }
}

// ---------------- pass 2: per-bucket fine CSR (round-9 per-wave form) --------
__global__ __launch_bounds__(256) void fine_build(const int* __restrict__ pairs,
                                                  const int* __restrict__ gcur,
                                                  int* __restrict__ beg,
                                                  int* __restrict__ ncnt,
                                                  int* __restrict__ adj, int N) {
    __shared__ int cnt[4][128], woff[4][128], cur[4][128];  // 6 KB
    __shared__ int sc[128];
    const int b = blockIdx.x;
    const int base = b << BSHIFT;
    const int nd = min(128, N - base);
    const int t = threadIdx.x;
    const int wv = t >> 6;
    const int s0 = b * SLOT;
    const int e1 = min(gcur[b], s0 + SLOT);
    for (int i = t; i < 512; i += 256) { (&cnt[0][0])[i] = 0; (&cur[0][0])[i] = 0; }
    __syncthreads();
    for (int i = s0 + t; i < e1; i += 256)
        atomicAdd(&cnt[wv][pairs[i] & 127], 1);
    __syncthreads();
    if (t < 128) {
        const int c0 = cnt[0][t], c1 = cnt[1][t], c2 = cnt[2][t];
        woff[0][t] = 0; woff[1][t] = c0; woff[2][t] = c0 + c1; woff[3][t] = c0 + c1 + c2;
        sc[t] = c0 + c1 + c2 + cnt[3][t];
    }
    __syncthreads();
    for (int off = 1; off < 128; off <<= 1) {            // inclusive scan of totals
        int v = (t < 128 && t >= off) ? sc[t - off] : 0;
        __syncthreads();
        if (t < 128) sc[t] += v;
        __syncthreads();
    }
    if (t < 128) {
        const int tot = cnt[0][t] + cnt[1][t] + cnt[2][t] + cnt[3][t];
        const int excl = sc[t] - tot;
        if (t < nd) { beg[base + t] = s0 + excl; ncnt[base + t] = tot; }
        woff[0][t] += excl; woff[1][t] += excl; woff[2][t] += excl; woff[3][t] += excl;
    }
    __syncthreads();
    for (int i = s0 + t; i < e1; i += 256) {             // same edge->wave map as count
        const int pkv = pairs[i];
        const int d = pkv & 127;
        const int pos = s0 + woff[wv][d] + atomicAdd(&cur[wv][d], 1);
        adj[pos] = pkv >> BSHIFT;
    }
}

// ---------------- per-dst softmax + weighted sum: TWO nodes per wave ---------
// (round-9 proven form)
__global__ __launch_bounds__(256) void aggregate(const unsigned short* __restrict__ z,
                                                 const float* __restrict__ s_src,
                                                 const float* __restrict__ s_dst,
                                                 const int* __restrict__ beg_,
                                                 const int* __restrict__ ncnt_,
                                                 const int* __restrict__ adj,
                                                 float* __restrict__ out, int N) {
    const int lane = threadIdx.x & 63;
    const int half = lane >> 5;
    const int l32  = lane & 31;
    const int q2   = l32 >> 4;
    const int l16  = lane & 15;
    const int hb   = half << 5;
    const int pairBase = blockIdx.x * 8 + (threadIdx.x >> 6) * 2;
    if (pairBase >= N) return;                            // wave-uniform
    const int nodeA = pairBase, nodeB = pairBase + 1;
    const int cA = ncnt_[nodeA], bA = beg_[nodeA];
    int cB = 0, bB = 0;
    if (nodeB < N) { cB = ncnt_[nodeB]; bB = beg_[nodeB]; }

    auto fma8 = [&](float* ac, float w, const uint4& v) {
        ac[0] = fmaf(w, BF_LO(v.x), ac[0]); ac[1] = fmaf(w, BF_HI(v.x), ac[1]);
        ac[2] = fmaf(w, BF_LO(v.y), ac[2]); ac[3] = fmaf(w, BF_HI(v.y), ac[3]);
        ac[4] = fmaf(w, BF_LO(v.z), ac[4]); ac[5] = fmaf(w, BF_HI(v.z), ac[5]);
        ac[6] = fmaf(w, BF_LO(v.w), ac[6]); ac[7] = fmaf(w, BF_HI(v.w), ac[7]);
    };

    if (max(cA, cB) <= 32) {
        const int myn = pairBase + half;
        const int mb  = half ? bB : bA;
        const int mc  = half ? cB : cA;                   // 0 if myn >= N
        const float sd = s_dst[myn < N ? myn : 0];
        int s = 0; float e = -INFINITY;
        if (l32 < mc) {
            s = adj[mb + l32];
            float tt = s_src[s] + sd;
            e = (tt >= 0.f) ? tt : NEG_SLOPE * tt;
        }
        // prefetch first 8 edges; they fly under the softmax reduce.
        int sj[4]; uint4 zv[4];
#pragma unroll
        for (int u = 0; u < 4; ++u) sj[u] = __shfl(s, hb + u * 2 + q2, 64);
#pragma unroll
        for (int u = 0; u < 4; ++u)
            zv[u] = *(const uint4*)&z[(size_t)sj[u] * D + l16 * 8];

        float mx = e;
#pragma unroll
        for (int o = 16; o; o >>= 1) mx = fmaxf(mx, __shfl_xor(mx, o, 64));
        float ex = (l32 < mc) ? __expf(e - mx) : 0.f;
        float sum = ex;
#pragma unroll
        for (int o = 16; o; o >>= 1) sum += __shfl_xor(sum, o, 64);
        const float inv = (mc > 0) ? 1.f / sum : 0.f;
        const float w = ex * inv;

        float a[8] = {0.f,0.f,0.f,0.f,0.f,0.f,0.f,0.f};
        float bacc[8] = {0.f,0.f,0.f,0.f,0.f,0.f,0.f,0.f};
#pragma unroll
        for (int u = 0; u < 4; ++u) {
            const int ji = u * 2 + q2;
            float wj = __shfl(w, hb + ji, 64);
            wj = (ji < mc) ? wj : 0.f;
            fma8((u & 1) ? bacc : a, wj, zv[u]);
        }
        for (int jj = 8; jj < mc; jj += 8) {
            int ji2[4]; float wj[4]; int sj2[4];
#pragma unroll
            for (int u = 0; u < 4; ++u) {
                ji2[u] = jj + u * 2 + q2;
                wj[u]  = __shfl(w, hb + ji2[u], 64);
                sj2[u] = __shfl(s, hb + ji2[u], 64);
                wj[u]  = (ji2[u] < mc) ? wj[u] : 0.f;
            }
            uint4 z0 = *(const uint4*)&z[(size_t)sj2[0] * D + l16 * 8];
            uint4 z1 = *(const uint4*)&z[(size_t)sj2[1] * D + l16 * 8];
            uint4 z2 = *(const uint4*)&z[(size_t)sj2[2] * D + l16 * 8];
            uint4 z3 = *(const uint4*)&z[(size_t)sj2[3] * D + l16 * 8];
            fma8(a, wj[0], z0);
            fma8(bacc, wj[1], z1);
            fma8(a, wj[2], z2);
            fma8(bacc, wj[3], z3);
        }
#pragma unroll
        for (int i = 0; i < 8; ++i) {
            a[i] += bacc[i];
            a[i] += __shfl_xor(a[i], 16, 64);            // cross-quad within half
        }
        if (q2 == 0 && myn < N) {
            float* o = &out[(size_t)myn * D + l16 * 8];
            *(float4*)o       = make_float4(a[0], a[1], a[2], a[3]);
            *(float4*)(o + 4) = make_float4(a[4], a[5], a[6], a[7]);
        }
        return;
    }

    // ---- fallback: generic full-wave strided path, nodes processed in turn --
    const int q = lane >> 4;
    for (int which = 0; which < 2; ++which) {
        const int myn = which ? nodeB : nodeA;
        if (myn >= N) break;
        const int mb = which ? bB : bA;
        const int mc = which ? cB : cA;
        const float sd = s_dst[myn];
        float a[8] = {0.f,0.f,0.f,0.f,0.f,0.f,0.f,0.f};
        float bacc[8] = {0.f,0.f,0.f,0.f,0.f,0.f,0.f,0.f};
        float mx = -INFINITY;
        for (int j = lane; j < mc; j += 64) {
            float tt = s_src[adj[mb + j]] + sd;
            tt = (tt >= 0.f) ? tt : NEG_SLOPE * tt;
            mx = fmaxf(mx, tt);
        }
#pragma unroll
        for (int o = 32; o; o >>= 1) mx = fmaxf(mx, __shfl_xor(mx, o, 64));
        float sum = 0.f;
        for (int j = lane; j < mc; j += 64) {
            float tt = s_src[adj[mb + j]] + sd;
            tt = (tt >= 0.f) ? tt : NEG_SLOPE * tt;
            sum += __expf(tt - mx);
        }
#pragma unroll
        for (int o = 32; o; o >>= 1) sum += __shfl_xor(sum, o, 64);
        const float inv = (mc > 0) ? 1.f / sum : 0.f;
        for (int base2 = 0; base2 < mc; base2 += 64) {
            const int cc = min(64, mc - base2);
            int s = 0; float w = 0.f;
            if (lane < cc) {
                s = adj[mb + base2 + lane];
                float tt = s_src[s] + sd;
                tt = (tt >= 0.f) ? tt : NEG_SLOPE * tt;
                w = __expf(tt - mx) * inv;
            }
            for (int jj = 0; jj < cc; jj += 8) {
                const int ja = jj + q;
                const int jb = ja + 4;
                float wa = __shfl(w, ja, 64); int sa = __shfl(s, ja, 64);
                float wb = __shfl(w, jb, 64); int sb = __shfl(s, jb, 64);
                wa = (ja < cc) ? wa : 0.f;
                wb = (jb < cc) ? wb : 0.f;
                uint4 za = *(const uint4*)&z[(size_t)sa * D + l16 * 8];
                uint4 zb = *(const uint4*)&z[(size_t)sb * D + l16 * 8];
                fma8(a, wa, za);
                fma8(bacc, wb, zb);
            }
        }
#pragma unroll
        for (int i = 0; i < 8; ++i) {
            a[i] += bacc[i];
            a[i] += __shfl_xor(a[i], 16, 64);
            a[i] += __shfl_xor(a[i], 32, 64);
        }
        if (q == 0) {
            float* o = &out[(size_t)myn * D + l16 * 8];
            *(float4*)o       = make_float4(a[0], a[1], a[2], a[3]);
            *(float4*)(o + 4) = make_float4(a[4], a[5], a[6], a[7]);
        }
    }
}

// ---------------- launch ----------------
extern "C" void kernel_launch(void* const* d_in, const int* in_sizes, int n_in,
                              void* d_out, int out_size, void* d_ws, size_t ws_size,
                              hipStream_t stream) {
    const float* h    = (const float*)d_in[0];
    const float* W    = (const float*)d_in[1];
    const float* aw   = (const float*)d_in[2];
    const int*   esrc = (const int*)d_in[3];
    const int*   edst = (const int*)d_in[4];
    float* out = (float*)d_out;

    const int N = in_sizes[0] / D;     // 100000
    const int E = in_sizes[3];         // 1600000
    const int NB1   = (N + 127) >> BSHIFT;
    const int NSORT = (E + SCHUNK - 1) / SCHUNK;
    const int NGEMM = (N + 63) / 64;

    char* p = (char*)d_ws;
    auto carve = [&](size_t bytes) {
        void* r = (void*)p;
        p += (bytes + 255) & ~size_t(255);
        return r;
    };
    unsigned short* z = (unsigned short*)carve(size_t(N) * D * sizeof(unsigned short));
    float* s_src  = (float*)carve(size_t(N) * sizeof(float));
    float* s_dst  = (float*)carve(size_t(N) * sizeof(float));
    int*   pairs  = (int*)carve(size_t(NB1) * SLOT * sizeof(int));
    int*   adj    = (int*)carve(size_t(NB1) * SLOT * sizeof(int));
    int*   beg    = (int*)carve(size_t(N) * sizeof(int));
    int*   ncnt   = (int*)carve(size_t(N) * sizeof(int));
    int*   gcur   = (int*)carve(size_t(B1) * sizeof(int));
    unsigned short* whi = (unsigned short*)carve(16384 * sizeof(unsigned short));
    unsigned short* wlo = (unsigned short*)carve(16384 * sizeof(unsigned short));
    (void)ws_size; (void)n_in; (void)out_size;

    prep_wfrag<<<64, 256, 0, stream>>>(W, whi, wlo, gcur);
    gemm_sort<<<NSORT + NGEMM, 256, 0, stream>>>(esrc, edst, gcur, pairs, E, NSORT,
                                                 h, whi, wlo, aw, z, s_src, s_dst, N);
    fine_build<<<NB1, 256, 0, stream>>>(pairs, gcur, beg, ncnt, adj, N);
    aggregate<<<(N + 7) / 8, 256, 0, stream>>>(z, s_src, s_dst, beg, ncnt, adj, out, N);
}

// Round 11
// 217.213 us; speedup vs baseline: 1.0780x; 1.0780x over previous
//
#include <hip/hip_runtime.h>

#define D 128            // D_IN == D_OUT == 128
#define NEG_SLOPE 0.01f
#define BSHIFT 7         // 128 dst values per coarse bucket
#define B1 1024          // max coarse buckets (N <= 131072)
#define SCHUNK 4096      // edges per sort block
#define SLOT 2560        // per-bucket slot capacity (mean 2048, sigma 45, max ~2250)

typedef __attribute__((ext_vector_type(8))) short short8;
typedef __attribute__((ext_vector_type(4))) float floatx4;

// bf16 helpers
__device__ __forceinline__ unsigned f2bf_rne(float x) {
    unsigned u = __float_as_uint(x);
    return (u + 0x7fffu + ((u >> 16) & 1u)) >> 16;
}
#define BF_LO(u) __uint_as_float((u) << 16)
#define BF_HI(u) __uint_as_float((u) & 0xffff0000u)

// ---------------- prep: W -> MFMA-fragment-ordered hi/lo bf16 + gcur init ----
__global__ __launch_bounds__(256) void prep_wfrag(const float* __restrict__ W,
                                                  unsigned short* __restrict__ whi,
                                                  unsigned short* __restrict__ wlo,
                                                  int* __restrict__ gcur) {
    if (blockIdx.x == 0) {
        for (int i = threadIdx.x; i < B1; i += 256) gcur[i] = i * SLOT;
    }
    const int idx = blockIdx.x * 256 + threadIdx.x;      // 0..16383
    const int j    = idx & 7;
    const int lane = (idx >> 3) & 63;
    const int tk   = idx >> 9;                           // ct*4+kk
    const int kk = tk & 3, ct = tk >> 2;
    const int k = kk * 32 + (lane >> 4) * 8 + j;
    const int n = ct * 16 + (lane & 15);
    const float x = W[k * D + n];
    const unsigned hi = f2bf_rne(x);
    const float hf = __uint_as_float(hi << 16);
    whi[idx] = (unsigned short)hi;
    wlo[idx] = (unsigned short)(__float_as_uint(x - hf) >> 16);
}

// ---------------- pass 1: block-local counting sort into slotted buckets -----
// (round-9 proven form: 1024 threads, int4 loads, shfl-up wave scan)
__global__ __launch_bounds__(1024) void sort_scatter(const int* __restrict__ esrc,
                                                     const int* __restrict__ edst,
                                                     int* __restrict__ gcur,
                                                     int* __restrict__ pairs, int E) {
    __shared__ int cnt[B1], exc[B1], gbs[B1], cur[B1];   // 16 KB
    __shared__ int spk[SCHUNK];                          // 16 KB sorted packed pairs
    __shared__ unsigned short sbkt[SCHUNK];              //  8 KB bucket of sorted entry
    __shared__ int wtot[16];                             // per-wave scan totals
    const int t = threadIdx.x;
    const int lane = t & 63, wv = t >> 6;
    cnt[t] = 0; cur[t] = 0;
    __syncthreads();

    const int e0 = blockIdx.x * SCHUNK;
    const int n  = min(SCHUNK, E - e0);

    // one int4 per thread: edges t*4 .. t*4+3
    int pk[4], bk[4];
    const int i0 = t * 4;
    if (i0 + 3 < n) {
        const int4 dv = *(const int4*)&edst[e0 + i0];
        const int4 sv = *(const int4*)&esrc[e0 + i0];
        const int dd[4] = {dv.x, dv.y, dv.z, dv.w};
        const int ss[4] = {sv.x, sv.y, sv.z, sv.w};
#pragma unroll
        for (int k = 0; k < 4; ++k) {
            bk[k] = dd[k] >> BSHIFT;
            pk[k] = (ss[k] << BSHIFT) | (dd[k] & 127);   // N <= 2^17: 17+7=24 bits
            atomicAdd(&cnt[bk[k]], 1);
        }
    } else {
#pragma unroll
        for (int k = 0; k < 4; ++k) {
            const int i = i0 + k;
            if (i < n) {
                const int d = edst[e0 + i];
                const int s = esrc[e0 + i];
                bk[k] = d >> BSHIFT;
                pk[k] = (s << BSHIFT) | (d & 127);
                atomicAdd(&cnt[bk[k]], 1);
            } else {
                bk[k] = -1;
            }
        }
    }
    __syncthreads();

    // exclusive scan over B1 buckets: wave shfl-scan + wave-total scan
    const int c = cnt[t];
    int incl = c;
#pragma unroll
    for (int o = 1; o < 64; o <<= 1) {
        int v = __shfl_up(incl, o, 64);
        if (lane >= o) incl += v;
    }
    if (lane == 63) wtot[wv] = incl;
    __syncthreads();
    int wpre = 0;
#pragma unroll
    for (int i = 0; i < 16; ++i) wpre += (i < wv) ? wtot[i] : 0;
    exc[t] = wpre + incl - c;
    // reserve this block's run in the slotted bucket region
    if (c > 0) gbs[t] = atomicAdd(&gcur[t], c);
    __syncthreads();

    // scatter into LDS sorted order
#pragma unroll
    for (int k = 0; k < 4; ++k) {
        if (bk[k] >= 0) {
            const int p = exc[bk[k]] + atomicAdd(&cur[bk[k]], 1);
            spk[p]  = pk[k];
            sbkt[p] = (unsigned short)bk[k];
        }
    }
    __syncthreads();

    // linear flush: consecutive i -> mostly same bucket -> contiguous stores.
    for (int i = t; i < n; i += 1024) {
        const int b = sbkt[i];
        const int pos = gbs[b] + (i - exc[b]);
        if (pos < (b + 1) * SLOT) pairs[pos] = spk[i];
    }
}

// ---------------- fused: fine_build blocks + gemm_zs blocks ------------------
// Independent kernels (fine needs pairs; gemm needs whi/wlo only). fine's LDS
// is 6.5 KB -> charged to gemm blocks it allows ~24 blocks/CU, far above
// gemm's VGPR bound: round-10's static-LDS failure mode is absent. Memory/
// atomic-bound fine blocks overlap MFMA-bound gemm blocks on the same CUs.
__global__ __launch_bounds__(256, 3) void fine_gemm(
        const int* __restrict__ pairs, const int* __restrict__ gcur,
        int* __restrict__ beg, int* __restrict__ ncnt, int* __restrict__ adj,
        int NFINE,
        const float* __restrict__ h, const unsigned short* __restrict__ whi,
        const unsigned short* __restrict__ wlo, const float* __restrict__ aw,
        unsigned short* __restrict__ z, float* __restrict__ s_src,
        float* __restrict__ s_dst, int N) {
    __shared__ int cnt[4][128], woff[4][128], cur[4][128];  // 6 KB
    __shared__ int sc[128];
    const int t = threadIdx.x;
    const int lane = t & 63;

    if ((int)blockIdx.x < NFINE) {
        // ================= fine_build body (round-9 per-wave form) ==========
        const int b = blockIdx.x;
        const int base = b << BSHIFT;
        const int nd = min(128, N - base);
        const int wv = t >> 6;
        const int s0 = b * SLOT;
        const int e1 = min(gcur[b], s0 + SLOT);
        for (int i = t; i < 512; i += 256) { (&cnt[0][0])[i] = 0; (&cur[0][0])[i] = 0; }
        __syncthreads();
        for (int i = s0 + t; i < e1; i += 256)
            atomicAdd(&cnt[wv][pairs[i] & 127], 1);
        __syncthreads();
        if (t < 128) {
            const int c0 = cnt[0][t], c1 = cnt[1][t], c2 = cnt[2][t];
            woff[0][t] = 0; woff[1][t] = c0; woff[2][t] = c0 + c1; woff[3][t] = c0 + c1 + c2;
            sc[t] = c0 + c1 + c2 + cnt[3][t];
        }
        __syncthreads();
        for (int off = 1; off < 128; off <<= 1) {        // inclusive scan of totals
            int v = (t < 128 && t >= off) ? sc[t - off] : 0;
            __syncthreads();
            if (t < 128) sc[t] += v;
            __syncthreads();
        }
        if (t < 128) {
            const int tot = cnt[0][t] + cnt[1][t] + cnt[2][t] + cnt[3][t];
            const int excl = sc[t] - tot;
            if (t < nd) { beg[base + t] = s0 + excl; ncnt[base + t] = tot; }
            woff[0][t] += excl; woff[1][t] += excl; woff[2][t] += excl; woff[3][t] += excl;
        }
        __syncthreads();
        for (int i = s0 + t; i < e1; i += 256) {         // same edge->wave map as count
            const int pkv = pairs[i];
            const int d = pkv & 127;
            const int pos = s0 + woff[wv][d] + atomicAdd(&cur[wv][d], 1);
            adj[pos] = pkv >> BSHIFT;
        }
        return;
    }

    // ================= gemm body (round-9 proven, no LDS use) ===============
    const int gbid = blockIdx.x - NFINE;
    const int quad = lane >> 4, l16 = lane & 15;
    const int rowbase = gbid * 64 + (t >> 6) * 16;
    const int arow = min(rowbase + l16, N - 1);          // clamp: unused C rows unsaved
    const float* __restrict__ hrow = h + (size_t)arow * D;

    // hoist all 8 h loads: independent, all in flight together
    float4 hx[8];
#pragma unroll
    for (int kk = 0; kk < 4; ++kk) {
        const int k0 = kk * 32 + quad * 8;
        hx[kk * 2]     = *(const float4*)&hrow[k0];
        hx[kk * 2 + 1] = *(const float4*)&hrow[k0 + 4];
    }
    union { short8 v; unsigned short u[8]; } ahi[4], alo[4];
#pragma unroll
    for (int kk = 0; kk < 4; ++kk) {
        const float xs[8] = {hx[kk*2].x, hx[kk*2].y, hx[kk*2].z, hx[kk*2].w,
                             hx[kk*2+1].x, hx[kk*2+1].y, hx[kk*2+1].z, hx[kk*2+1].w};
#pragma unroll
        for (int i = 0; i < 8; ++i) {
            const unsigned hi = f2bf_rne(xs[i]);
            const float hf = __uint_as_float(hi << 16);
            ahi[kk].u[i] = (unsigned short)hi;
            alo[kk].u[i] = (unsigned short)(__float_as_uint(xs[i] - hf) >> 16);
        }
    }

    floatx4 acc[8];
#pragma unroll
    for (int ct = 0; ct < 8; ++ct) acc[ct] = (floatx4){0.f, 0.f, 0.f, 0.f};

#pragma unroll
    for (int kk = 0; kk < 4; ++kk)
#pragma unroll
        for (int ct = 0; ct < 8; ++ct) {
            const int fo = ((ct * 4 + kk) * 64 + lane) * 8;   // 16B-aligned
            short8 bhi = *(const short8*)&whi[fo];
            short8 blo = *(const short8*)&wlo[fo];
            acc[ct] = __builtin_amdgcn_mfma_f32_16x16x32_bf16(ahi[kk].v, bhi, acc[ct], 0, 0, 0);
            acc[ct] = __builtin_amdgcn_mfma_f32_16x16x32_bf16(alo[kk].v, bhi, acc[ct], 0, 0, 0);
            acc[ct] = __builtin_amdgcn_mfma_f32_16x16x32_bf16(ahi[kk].v, blo, acc[ct], 0, 0, 0);
        }

    // z store (bf16) from C-frags: elem (row=quad*4+reg, col=ct*16+l16)
#pragma unroll
    for (int ct = 0; ct < 8; ++ct)
#pragma unroll
        for (int reg = 0; reg < 4; ++reg) {
            int r = rowbase + quad * 4 + reg;
            if (r < N)
                z[(size_t)r * D + ct * 16 + l16] = (unsigned short)f2bf_rne(acc[ct][reg]);
        }

    // fused scores: per-lane partials for this lane's 4 rows, reduce across l16
    float ps[4] = {0.f, 0.f, 0.f, 0.f}, pd[4] = {0.f, 0.f, 0.f, 0.f};
#pragma unroll
    for (int ct = 0; ct < 8; ++ct) {
        float as = aw[ct * 16 + l16];
        float ad = aw[128 + ct * 16 + l16];
#pragma unroll
        for (int reg = 0; reg < 4; ++reg) {
            ps[reg] = fmaf(acc[ct][reg], as, ps[reg]);
            pd[reg] = fmaf(acc[ct][reg], ad, pd[reg]);
        }
    }
#pragma unroll
    for (int reg = 0; reg < 4; ++reg)
#pragma unroll
        for (int o = 1; o < 16; o <<= 1) {               // all 64 lanes active
            ps[reg] += __shfl_xor(ps[reg], o, 64);
            pd[reg] += __shfl_xor(pd[reg], o, 64);
        }
    if (l16 == 0) {
#pragma unroll
        for (int reg = 0; reg < 4; ++reg) {
            int r = rowbase + quad * 4 + reg;
            if (r < N) { s_src[r] = ps[reg]; s_dst[r] = pd[reg]; }
        }
    }
}

// ---------------- per-dst softmax + weighted sum: TWO nodes per wave ---------
// (round-9 proven form)
__global__ __launch_bounds__(256) void aggregate(const unsigned short* __restrict__ z,
                                                 const float* __restrict__ s_src,
                                                 const float* __restrict__ s_dst,
                                                 const int* __restrict__ beg_,
                                                 const int* __restrict__ ncnt_,
                                                 const int* __restrict__ adj,
                                                 float* __restrict__ out, int N) {
    const int lane = threadIdx.x & 63;
    const int half = lane >> 5;
    const int l32  = lane & 31;
    const int q2   = l32 >> 4;
    const int l16  = lane & 15;
    const int hb   = half << 5;
    const int pairBase = blockIdx.x * 8 + (threadIdx.x >> 6) * 2;
    if (pairBase >= N) return;                            // wave-uniform
    const int nodeA = pairBase, nodeB = pairBase + 1;
    const int cA = ncnt_[nodeA], bA = beg_[nodeA];
    int cB = 0, bB = 0;
    if (nodeB < N) { cB = ncnt_[nodeB]; bB = beg_[nodeB]; }

    auto fma8 = [&](float* ac, float w, const uint4& v) {
        ac[0] = fmaf(w, BF_LO(v.x), ac[0]); ac[1] = fmaf(w, BF_HI(v.x), ac[1]);
        ac[2] = fmaf(w, BF_LO(v.y), ac[2]); ac[3] = fmaf(w, BF_HI(v.y), ac[3]);
        ac[4] = fmaf(w, BF_LO(v.z), ac[4]); ac[5] = fmaf(w, BF_HI(v.z), ac[5]);
        ac[6] = fmaf(w, BF_LO(v.w), ac[6]); ac[7] = fmaf(w, BF_HI(v.w), ac[7]);
    };

    if (max(cA, cB) <= 32) {
        const int myn = pairBase + half;
        const int mb  = half ? bB : bA;
        const int mc  = half ? cB : cA;                   // 0 if myn >= N
        const float sd = s_dst[myn < N ? myn : 0];
        int s = 0; float e = -INFINITY;
        if (l32 < mc) {
            s = adj[mb + l32];
            float tt = s_src[s] + sd;
            e = (tt >= 0.f) ? tt : NEG_SLOPE * tt;
        }
        // prefetch first 8 edges; they fly under the softmax reduce.
        int sj[4]; uint4 zv[4];
#pragma unroll
        for (int u = 0; u < 4; ++u) sj[u] = __shfl(s, hb + u * 2 + q2, 64);
#pragma unroll
        for (int u = 0; u < 4; ++u)
            zv[u] = *(const uint4*)&z[(size_t)sj[u] * D + l16 * 8];

        float mx = e;
#pragma unroll
        for (int o = 16; o; o >>= 1) mx = fmaxf(mx, __shfl_xor(mx, o, 64));
        float ex = (l32 < mc) ? __expf(e - mx) : 0.f;
        float sum = ex;
#pragma unroll
        for (int o = 16; o; o >>= 1) sum += __shfl_xor(sum, o, 64);
        const float inv = (mc > 0) ? 1.f / sum : 0.f;
        const float w = ex * inv;

        float a[8] = {0.f,0.f,0.f,0.f,0.f,0.f,0.f,0.f};
        float bacc[8] = {0.f,0.f,0.f,0.f,0.f,0.f,0.f,0.f};
#pragma unroll
        for (int u = 0; u < 4; ++u) {
            const int ji = u * 2 + q2;
            float wj = __shfl(w, hb + ji, 64);
            wj = (ji < mc) ? wj : 0.f;
            fma8((u & 1) ? bacc : a, wj, zv[u]);
        }
        for (int jj = 8; jj < mc; jj += 8) {
            int ji2[4]; float wj[4]; int sj2[4];
#pragma unroll
            for (int u = 0; u < 4; ++u) {
                ji2[u] = jj + u * 2 + q2;
                wj[u]  = __shfl(w, hb + ji2[u], 64);
                sj2[u] = __shfl(s, hb + ji2[u], 64);
                wj[u]  = (ji2[u] < mc) ? wj[u] : 0.f;
            }
            uint4 z0 = *(const uint4*)&z[(size_t)sj2[0] * D + l16 * 8];
            uint4 z1 = *(const uint4*)&z[(size_t)sj2[1] * D + l16 * 8];
            uint4 z2 = *(const uint4*)&z[(size_t)sj2[2] * D + l16 * 8];
            uint4 z3 = *(const uint4*)&z[(size_t)sj2[3] * D + l16 * 8];
            fma8(a, wj[0], z0);
            fma8(bacc, wj[1], z1);
            fma8(a, wj[2], z2);
            fma8(bacc, wj[3], z3);
        }
#pragma unroll
        for (int i = 0; i < 8; ++i) {
            a[i] += bacc[i];
            a[i] += __shfl_xor(a[i], 16, 64);            // cross-quad within half
        }
        if (q2 == 0 && myn < N) {
            float* o = &out[(size_t)myn * D + l16 * 8];
            *(float4*)o       = make_float4(a[0], a[1], a[2], a[3]);
            *(float4*)(o + 4) = make_float4(a[4], a[5], a[6], a[7]);
        }
        return;
    }

    // ---- fallback: generic full-wave strided path, nodes processed in turn --
    const int q = lane >> 4;
    for (int which = 0; which < 2; ++which) {
        const int myn = which ? nodeB : nodeA;
        if (myn >= N) break;
        const int mb = which ? bB : bA;
        const int mc = which ? cB : cA;
        const float sd = s_dst[myn];
        float a[8] = {0.f,0.f,0.f,0.f,0.f,0.f,0.f,0.f};
        float bacc[8] = {0.f,0.f,0.f,0.f,0.f,0.f,0.f,0.f};
        float mx = -INFINITY;
        for (int j = lane; j < mc; j += 64) {
            float tt = s_src[adj[mb + j]] + sd;
            tt = (tt >= 0.f) ? tt : NEG_SLOPE * tt;
            mx = fmaxf(mx, tt);
        }
#pragma unroll
        for (int o = 32; o; o >>= 1) mx = fmaxf(mx, __shfl_xor(mx, o, 64));
        float sum = 0.f;
        for (int j = lane; j < mc; j += 64) {
            float tt = s_src[adj[mb + j]] + sd;
            tt = (tt >= 0.f) ? tt : NEG_SLOPE * tt;
            sum += __expf(tt - mx);
        }
#pragma unroll
        for (int o = 32; o; o >>= 1) sum += __shfl_xor(sum, o, 64);
        const float inv = (mc > 0) ? 1.f / sum : 0.f;
        for (int base2 = 0; base2 < mc; base2 += 64) {
            const int cc = min(64, mc - base2);
            int s = 0; float w = 0.f;
            if (lane < cc) {
                s = adj[mb + base2 + lane];
                float tt = s_src[s] + sd;
                tt = (tt >= 0.f) ? tt : NEG_SLOPE * tt;
                w = __expf(tt - mx) * inv;
            }
            for (int jj = 0; jj < cc; jj += 8) {
                const int ja = jj + q;
                const int jb = ja + 4;
                float wa = __shfl(w, ja, 64); int sa = __shfl(s, ja, 64);
                float wb = __shfl(w, jb, 64); int sb = __shfl(s, jb, 64);
                wa = (ja < cc) ? wa : 0.f;
                wb = (jb < cc) ? wb : 0.f;
                uint4 za = *(const uint4*)&z[(size_t)sa * D + l16 * 8];
                uint4 zb = *(const uint4*)&z[(size_t)sb * D + l16 * 8];
                fma8(a, wa, za);
                fma8(bacc, wb, zb);
            }
        }
#pragma unroll
        for (int i = 0; i < 8; ++i) {
            a[i] += bacc[i];
            a[i] += __shfl_xor(a[i], 16, 64);
            a[i] += __shfl_xor(a[i], 32, 64);
        }
        if (q == 0) {
            float* o = &out[(size_t)myn * D + l16 * 8];
            *(float4*)o       = make_float4(a[0], a[1], a[2], a[3]);
            *(float4*)(o + 4) = make_float4(a[4], a[5], a[6], a[7]);
        }
    }
}

// ---------------- launch ----------------
extern "C" void kernel_launch(void* const* d_in, const int* in_sizes, int n_in,
                              void* d_out, int out_size, void* d_ws, size_t ws_size,
                              hipStream_t stream) {
    const float* h    = (const float*)d_in[0];
    const float* W    = (const float*)d_in[1];
    const float* aw   = (const float*)d_in[2];
    const int*   esrc = (const int*)d_in[3];
    const int*   edst = (const int*)d_in[4];
    float* out = (float*)d_out;

    const int N = in_sizes[0] / D;     // 100000
    const int E = in_sizes[3];         // 1600000
    const int NB1   = (N + 127) >> BSHIFT;     // fine blocks (782)
    const int NSORT = (E + SCHUNK - 1) / SCHUNK;
    const int NGEMM = (N + 63) / 64;           // gemm blocks (1563)

    char* p = (char*)d_ws;
    auto carve = [&](size_t bytes) {
        void* r = (void*)p;
        p += (bytes + 255) & ~size_t(255);
        return r;
    };
    unsigned short* z = (unsigned short*)carve(size_t(N) * D * sizeof(unsigned short));
    float* s_src  = (float*)carve(size_t(N) * sizeof(float));
    float* s_dst  = (float*)carve(size_t(N) * sizeof(float));
    int*   pairs  = (int*)carve(size_t(NB1) * SLOT * sizeof(int));
    int*   adj    = (int*)carve(size_t(NB1) * SLOT * sizeof(int));
    int*   beg    = (int*)carve(size_t(N) * sizeof(int));
    int*   ncnt   = (int*)carve(size_t(N) * sizeof(int));
    int*   gcur   = (int*)carve(size_t(B1) * sizeof(int));
    unsigned short* whi = (unsigned short*)carve(16384 * sizeof(unsigned short));
    unsigned short* wlo = (unsigned short*)carve(16384 * sizeof(unsigned short));
    (void)ws_size; (void)n_in; (void)out_size;

    prep_wfrag<<<64, 256, 0, stream>>>(W, whi, wlo, gcur);
    sort_scatter<<<NSORT, 1024, 0, stream>>>(esrc, edst, gcur, pairs, E);
    fine_gemm<<<NB1 + NGEMM, 256, 0, stream>>>(pairs, gcur, beg, ncnt, adj, NB1,
                                               h, whi, wlo, aw, z, s_src, s_dst, N);
    aggregate<<<(N + 7) / 8, 256, 0, stream>>>(z, s_src, s_dst, beg, ncnt, adj, out, N);
}

// Round 12
// 214.379 us; speedup vs baseline: 1.0923x; 1.0132x over previous
//
#include <hip/hip_runtime.h>

#define D 128            // D_IN == D_OUT == 128
#define NEG_SLOPE 0.01f
#define BSHIFT 7         // 128 dst values per coarse bucket
#define B1 1024          // max coarse buckets (N <= 131072)
#define SCHUNK 4096      // edges per sort block
#define SLOT 2560        // per-bucket slot capacity (mean 2048, sigma 45, max ~2250)

typedef __attribute__((ext_vector_type(8))) short short8;
typedef __attribute__((ext_vector_type(4))) float floatx4;

// bf16 helpers
__device__ __forceinline__ unsigned f2bf_rne(float x) {
    unsigned u = __float_as_uint(x);
    return (u + 0x7fffu + ((u >> 16) & 1u)) >> 16;
}
#define BF_LO(u) __uint_as_float((u) << 16)
#define BF_HI(u) __uint_as_float((u) & 0xffff0000u)

// ---------------- fused: sort_scatter blocks + prep_wfrag blocks -------------
// gcur is RELATIVE (memset to 0 on the stream), so prep no longer has to run
// first: prep blocks (16 x 1024 threads, LDS-free, W-only) ride in the same
// dispatch as the sort. One launch instead of two.
__global__ __launch_bounds__(1024) void sort_prep(
        const int* __restrict__ esrc, const int* __restrict__ edst,
        int* __restrict__ gcur, int* __restrict__ pairs, int E, int NSORT,
        const float* __restrict__ W, unsigned short* __restrict__ whi,
        unsigned short* __restrict__ wlo) {
    __shared__ int cnt[B1], exc[B1], gbs[B1], cur[B1];   // 16 KB
    __shared__ int spk[SCHUNK];                          // 16 KB sorted packed pairs
    __shared__ unsigned short sbkt[SCHUNK];              //  8 KB bucket of sorted entry
    __shared__ int wtot[16];                             // per-wave scan totals
    const int t = threadIdx.x;

    if ((int)blockIdx.x >= NSORT) {
        // ---- prep body: W -> MFMA-fragment-ordered hi/lo bf16 ----
        // idx = ((ct*4+kk)*64 + lane)*8 + j holds W[kk*32+(lane>>4)*8+j][ct*16+(lane&15)]
        const int idx = (blockIdx.x - NSORT) * 1024 + t; // 0..16383
        const int j    = idx & 7;
        const int lane = (idx >> 3) & 63;
        const int tk   = idx >> 9;                       // ct*4+kk
        const int kk = tk & 3, ct = tk >> 2;
        const int k = kk * 32 + (lane >> 4) * 8 + j;
        const int n = ct * 16 + (lane & 15);
        const float x = W[k * D + n];
        const unsigned hi = f2bf_rne(x);
        const float hf = __uint_as_float(hi << 16);
        whi[idx] = (unsigned short)hi;
        wlo[idx] = (unsigned short)(__float_as_uint(x - hf) >> 16);
        return;
    }

    // ---- sort body (round-9 proven form; gcur now relative) ----
    const int lane = t & 63, wv = t >> 6;
    cnt[t] = 0; cur[t] = 0;
    __syncthreads();

    const int e0 = blockIdx.x * SCHUNK;
    const int n  = min(SCHUNK, E - e0);

    // one int4 per thread: edges t*4 .. t*4+3
    int pk[4], bk[4];
    const int i0 = t * 4;
    if (i0 + 3 < n) {
        const int4 dv = *(const int4*)&edst[e0 + i0];
        const int4 sv = *(const int4*)&esrc[e0 + i0];
        const int dd[4] = {dv.x, dv.y, dv.z, dv.w};
        const int ss[4] = {sv.x, sv.y, sv.z, sv.w};
#pragma unroll
        for (int k = 0; k < 4; ++k) {
            bk[k] = dd[k] >> BSHIFT;
            pk[k] = (ss[k] << BSHIFT) | (dd[k] & 127);   // N <= 2^17: 17+7=24 bits
            atomicAdd(&cnt[bk[k]], 1);
        }
    } else {
#pragma unroll
        for (int k = 0; k < 4; ++k) {
            const int i = i0 + k;
            if (i < n) {
                const int d = edst[e0 + i];
                const int s = esrc[e0 + i];
                bk[k] = d >> BSHIFT;
                pk[k] = (s << BSHIFT) | (d & 127);
                atomicAdd(&cnt[bk[k]], 1);
            } else {
                bk[k] = -1;
            }
        }
    }
    __syncthreads();

    // exclusive scan over B1 buckets: wave shfl-scan + wave-total scan
    const int c = cnt[t];
    int incl = c;
#pragma unroll
    for (int o = 1; o < 64; o <<= 1) {
        int v = __shfl_up(incl, o, 64);
        if (lane >= o) incl += v;
    }
    if (lane == 63) wtot[wv] = incl;
    __syncthreads();
    int wpre = 0;
#pragma unroll
    for (int i = 0; i < 16; ++i) wpre += (i < wv) ? wtot[i] : 0;
    exc[t] = wpre + incl - c;
    // reserve this block's run (relative offset within bucket slot)
    if (c > 0) gbs[t] = atomicAdd(&gcur[t], c);
    __syncthreads();

    // scatter into LDS sorted order
#pragma unroll
    for (int k = 0; k < 4; ++k) {
        if (bk[k] >= 0) {
            const int p = exc[bk[k]] + atomicAdd(&cur[bk[k]], 1);
            spk[p]  = pk[k];
            sbkt[p] = (unsigned short)bk[k];
        }
    }
    __syncthreads();

    // linear flush: consecutive i -> mostly same bucket -> contiguous stores.
    // Guard against (astronomically unlikely) slot overflow: drop, don't fault.
    for (int i = t; i < n; i += 1024) {
        const int b = sbkt[i];
        const int off = gbs[b] + (i - exc[b]);
        if (off < SLOT) pairs[b * SLOT + off] = spk[i];
    }
}

// ---------------- fused: fine_build blocks + gemm_zs blocks ------------------
// (round-11 proven form; gcur relative)
__global__ __launch_bounds__(256, 3) void fine_gemm(
        const int* __restrict__ pairs, const int* __restrict__ gcur,
        int* __restrict__ beg, int* __restrict__ ncnt, int* __restrict__ adj,
        int NFINE,
        const float* __restrict__ h, const unsigned short* __restrict__ whi,
        const unsigned short* __restrict__ wlo, const float* __restrict__ aw,
        unsigned short* __restrict__ z, float* __restrict__ s_src,
        float* __restrict__ s_dst, int N) {
    __shared__ int cnt[4][128], woff[4][128], cur[4][128];  // 6 KB
    __shared__ int sc[128];
    const int t = threadIdx.x;
    const int lane = t & 63;

    if ((int)blockIdx.x < NFINE) {
        // ================= fine_build body (per-wave histograms) ============
        const int b = blockIdx.x;
        const int base = b << BSHIFT;
        const int nd = min(128, N - base);
        const int wv = t >> 6;
        const int s0 = b * SLOT;
        const int e1 = s0 + min(gcur[b], SLOT);
        for (int i = t; i < 512; i += 256) { (&cnt[0][0])[i] = 0; (&cur[0][0])[i] = 0; }
        __syncthreads();
        for (int i = s0 + t; i < e1; i += 256)
            atomicAdd(&cnt[wv][pairs[i] & 127], 1);
        __syncthreads();
        if (t < 128) {
            const int c0 = cnt[0][t], c1 = cnt[1][t], c2 = cnt[2][t];
            woff[0][t] = 0; woff[1][t] = c0; woff[2][t] = c0 + c1; woff[3][t] = c0 + c1 + c2;
            sc[t] = c0 + c1 + c2 + cnt[3][t];
        }
        __syncthreads();
        for (int off = 1; off < 128; off <<= 1) {        // inclusive scan of totals
            int v = (t < 128 && t >= off) ? sc[t - off] : 0;
            __syncthreads();
            if (t < 128) sc[t] += v;
            __syncthreads();
        }
        if (t < 128) {
            const int tot = cnt[0][t] + cnt[1][t] + cnt[2][t] + cnt[3][t];
            const int excl = sc[t] - tot;
            if (t < nd) { beg[base + t] = s0 + excl; ncnt[base + t] = tot; }
            woff[0][t] += excl; woff[1][t] += excl; woff[2][t] += excl; woff[3][t] += excl;
        }
        __syncthreads();
        for (int i = s0 + t; i < e1; i += 256) {         // same edge->wave map as count
            const int pkv = pairs[i];
            const int d = pkv & 127;
            const int pos = s0 + woff[wv][d] + atomicAdd(&cur[wv][d], 1);
            adj[pos] = pkv >> BSHIFT;
        }
        return;
    }

    // ================= gemm body (round-9 proven, no LDS use) ===============
    const int gbid = blockIdx.x - NFINE;
    const int quad = lane >> 4, l16 = lane & 15;
    const int rowbase = gbid * 64 + (t >> 6) * 16;
    const int arow = min(rowbase + l16, N - 1);          // clamp: unused C rows unsaved
    const float* __restrict__ hrow = h + (size_t)arow * D;

    // hoist all 8 h loads: independent, all in flight together
    float4 hx[8];
#pragma unroll
    for (int kk = 0; kk < 4; ++kk) {
        const int k0 = kk * 32 + quad * 8;
        hx[kk * 2]     = *(const float4*)&hrow[k0];
        hx[kk * 2 + 1] = *(const float4*)&hrow[k0 + 4];
    }
    union { short8 v; unsigned short u[8]; } ahi[4], alo[4];
#pragma unroll
    for (int kk = 0; kk < 4; ++kk) {
        const float xs[8] = {hx[kk*2].x, hx[kk*2].y, hx[kk*2].z, hx[kk*2].w,
                             hx[kk*2+1].x, hx[kk*2+1].y, hx[kk*2+1].z, hx[kk*2+1].w};
#pragma unroll
        for (int i = 0; i < 8; ++i) {
            const unsigned hi = f2bf_rne(xs[i]);
            const float hf = __uint_as_float(hi << 16);
            ahi[kk].u[i] = (unsigned short)hi;
            alo[kk].u[i] = (unsigned short)(__float_as_uint(xs[i] - hf) >> 16);
        }
    }

    floatx4 acc[8];
#pragma unroll
    for (int ct = 0; ct < 8; ++ct) acc[ct] = (floatx4){0.f, 0.f, 0.f, 0.f};

#pragma unroll
    for (int kk = 0; kk < 4; ++kk)
#pragma unroll
        for (int ct = 0; ct < 8; ++ct) {
            const int fo = ((ct * 4 + kk) * 64 + lane) * 8;   // 16B-aligned
            short8 bhi = *(const short8*)&whi[fo];
            short8 blo = *(const short8*)&wlo[fo];
            acc[ct] = __builtin_amdgcn_mfma_f32_16x16x32_bf16(ahi[kk].v, bhi, acc[ct], 0, 0, 0);
            acc[ct] = __builtin_amdgcn_mfma_f32_16x16x32_bf16(alo[kk].v, bhi, acc[ct], 0, 0, 0);
            acc[ct] = __builtin_amdgcn_mfma_f32_16x16x32_bf16(ahi[kk].v, blo, acc[ct], 0, 0, 0);
        }

    // z store (bf16) from C-frags: elem (row=quad*4+reg, col=ct*16+l16)
#pragma unroll
    for (int ct = 0; ct < 8; ++ct)
#pragma unroll
        for (int reg = 0; reg < 4; ++reg) {
            int r = rowbase + quad * 4 + reg;
            if (r < N)
                z[(size_t)r * D + ct * 16 + l16] = (unsigned short)f2bf_rne(acc[ct][reg]);
        }

    // fused scores: per-lane partials for this lane's 4 rows, reduce across l16
    float ps[4] = {0.f, 0.f, 0.f, 0.f}, pd[4] = {0.f, 0.f, 0.f, 0.f};
#pragma unroll
    for (int ct = 0; ct < 8; ++ct) {
        float as = aw[ct * 16 + l16];
        float ad = aw[128 + ct * 16 + l16];
#pragma unroll
        for (int reg = 0; reg < 4; ++reg) {
            ps[reg] = fmaf(acc[ct][reg], as, ps[reg]);
            pd[reg] = fmaf(acc[ct][reg], ad, pd[reg]);
        }
    }
#pragma unroll
    for (int reg = 0; reg < 4; ++reg)
#pragma unroll
        for (int o = 1; o < 16; o <<= 1) {               // all 64 lanes active
            ps[reg] += __shfl_xor(ps[reg], o, 64);
            pd[reg] += __shfl_xor(pd[reg], o, 64);
        }
    if (l16 == 0) {
#pragma unroll
        for (int reg = 0; reg < 4; ++reg) {
            int r = rowbase + quad * 4 + reg;
            if (r < N) { s_src[r] = ps[reg]; s_dst[r] = pd[reg]; }
        }
    }
}

// ---------------- per-dst softmax + weighted sum: TWO nodes per wave ---------
// vs round 11: deg<=32 path is 2-deep group-pipelined -- while fma-ing group
// g's 4 z-rows, group g+1's 4 loads are in flight (8 uint4/lane outstanding
// vs 4). Kernel is latency-bound on L2 misses (z row gathers); doubling
// outstanding misses cuts wait stalls.
__global__ __launch_bounds__(256) void aggregate(const unsigned short* __restrict__ z,
                                                 const float* __restrict__ s_src,
                                                 const float* __restrict__ s_dst,
                                                 const int* __restrict__ beg_,
                                                 const int* __restrict__ ncnt_,
                                                 const int* __restrict__ adj,
                                                 float* __restrict__ out, int N) {
    const int lane = threadIdx.x & 63;
    const int half = lane >> 5;
    const int l32  = lane & 31;
    const int q2   = l32 >> 4;
    const int l16  = lane & 15;
    const int hb   = half << 5;
    const int pairBase = blockIdx.x * 8 + (threadIdx.x >> 6) * 2;
    if (pairBase >= N) return;                            // wave-uniform
    const int nodeA = pairBase, nodeB = pairBase + 1;
    const int cA = ncnt_[nodeA], bA = beg_[nodeA];
    int cB = 0, bB = 0;
    if (nodeB < N) { cB = ncnt_[nodeB]; bB = beg_[nodeB]; }

    auto fma8 = [&](float* ac, float w, const uint4& v) {
        ac[0] = fmaf(w, BF_LO(v.x), ac[0]); ac[1] = fmaf(w, BF_HI(v.x), ac[1]);
        ac[2] = fmaf(w, BF_LO(v.y), ac[2]); ac[3] = fmaf(w, BF_HI(v.y), ac[3]);
        ac[4] = fmaf(w, BF_LO(v.z), ac[4]); ac[5] = fmaf(w, BF_HI(v.z), ac[5]);
        ac[6] = fmaf(w, BF_LO(v.w), ac[6]); ac[7] = fmaf(w, BF_HI(v.w), ac[7]);
    };

    if (max(cA, cB) <= 32) {
        const int myn = pairBase + half;
        const int mb  = half ? bB : bA;
        const int mc  = half ? cB : cA;                   // 0 if myn >= N
        const float sd = s_dst[myn < N ? myn : 0];
        int s = 0; float e = -INFINITY;
        if (l32 < mc) {
            s = adj[mb + l32];
            float tt = s_src[s] + sd;
            e = (tt >= 0.f) ? tt : NEG_SLOPE * tt;
        }
        // prefetch group 0 (edges 0..7); flies under the softmax reduce.
        // (invalid slots read z row of s=0: valid address, weight forced 0.)
        uint4 g0, g1, g2, g3;
        {
            const int s0_ = __shfl(s, hb + 0 + q2, 64);
            const int s1_ = __shfl(s, hb + 2 + q2, 64);
            const int s2_ = __shfl(s, hb + 4 + q2, 64);
            const int s3_ = __shfl(s, hb + 6 + q2, 64);
            g0 = *(const uint4*)&z[(size_t)s0_ * D + l16 * 8];
            g1 = *(const uint4*)&z[(size_t)s1_ * D + l16 * 8];
            g2 = *(const uint4*)&z[(size_t)s2_ * D + l16 * 8];
            g3 = *(const uint4*)&z[(size_t)s3_ * D + l16 * 8];
        }

        float mx = e;
#pragma unroll
        for (int o = 16; o; o >>= 1) mx = fmaxf(mx, __shfl_xor(mx, o, 64));
        float ex = (l32 < mc) ? __expf(e - mx) : 0.f;
        float sum = ex;
#pragma unroll
        for (int o = 16; o; o >>= 1) sum += __shfl_xor(sum, o, 64);
        const float inv = (mc > 0) ? 1.f / sum : 0.f;
        const float w = ex * inv;

        float a[8] = {0.f,0.f,0.f,0.f,0.f,0.f,0.f,0.f};
        float bacc[8] = {0.f,0.f,0.f,0.f,0.f,0.f,0.f,0.f};
        int jj = 0;
        while (true) {
            const int nj = jj + 8;
            const bool more = nj < mc;                   // half-uniform
            uint4 n0, n1, n2, n3;
            if (more) {                                  // issue next group now
                const int t0 = __shfl(s, hb + nj + 0 + q2, 64);
                const int t1 = __shfl(s, hb + nj + 2 + q2, 64);
                const int t2 = __shfl(s, hb + nj + 4 + q2, 64);
                const int t3 = __shfl(s, hb + nj + 6 + q2, 64);
                n0 = *(const uint4*)&z[(size_t)t0 * D + l16 * 8];
                n1 = *(const uint4*)&z[(size_t)t1 * D + l16 * 8];
                n2 = *(const uint4*)&z[(size_t)t2 * D + l16 * 8];
                n3 = *(const uint4*)&z[(size_t)t3 * D + l16 * 8];
            }
            // consume current group (edges jj..jj+7) while next is in flight
            {
                float w0 = __shfl(w, hb + jj + 0 + q2, 64);
                float w1 = __shfl(w, hb + jj + 2 + q2, 64);
                float w2 = __shfl(w, hb + jj + 4 + q2, 64);
                float w3 = __shfl(w, hb + jj + 6 + q2, 64);
                w0 = (jj + 0 + q2 < mc) ? w0 : 0.f;
                w1 = (jj + 2 + q2 < mc) ? w1 : 0.f;
                w2 = (jj + 4 + q2 < mc) ? w2 : 0.f;
                w3 = (jj + 6 + q2 < mc) ? w3 : 0.f;
                fma8(a, w0, g0); fma8(bacc, w1, g1);
                fma8(a, w2, g2); fma8(bacc, w3, g3);
            }
            if (!more) break;
            g0 = n0; g1 = n1; g2 = n2; g3 = n3;
            jj = nj;
        }
#pragma unroll
        for (int i = 0; i < 8; ++i) {
            a[i] += bacc[i];
            a[i] += __shfl_xor(a[i], 16, 64);            // cross-quad within half
        }
        if (q2 == 0 && myn < N) {
            float* o = &out[(size_t)myn * D + l16 * 8];
            *(float4*)o       = make_float4(a[0], a[1], a[2], a[3]);
            *(float4*)(o + 4) = make_float4(a[4], a[5], a[6], a[7]);
        }
        return;
    }

    // ---- fallback: generic full-wave strided path, nodes processed in turn --
    const int q = lane >> 4;
    for (int which = 0; which < 2; ++which) {
        const int myn = which ? nodeB : nodeA;
        if (myn >= N) break;
        const int mb = which ? bB : bA;
        const int mc = which ? cB : cA;
        const float sd = s_dst[myn];
        float a[8] = {0.f,0.f,0.f,0.f,0.f,0.f,0.f,0.f};
        float bacc[8] = {0.f,0.f,0.f,0.f,0.f,0.f,0.f,0.f};
        float mx = -INFINITY;
        for (int j = lane; j < mc; j += 64) {
            float tt = s_src[adj[mb + j]] + sd;
            tt = (tt >= 0.f) ? tt : NEG_SLOPE * tt;
            mx = fmaxf(mx, tt);
        }
#pragma unroll
        for (int o = 32; o; o >>= 1) mx = fmaxf(mx, __shfl_xor(mx, o, 64));
        float sum = 0.f;
        for (int j = lane; j < mc; j += 64) {
            float tt = s_src[adj[mb + j]] + sd;
            tt = (tt >= 0.f) ? tt : NEG_SLOPE * tt;
            sum += __expf(tt - mx);
        }
#pragma unroll
        for (int o = 32; o; o >>= 1) sum += __shfl_xor(sum, o, 64);
        const float inv = (mc > 0) ? 1.f / sum : 0.f;
        for (int base2 = 0; base2 < mc; base2 += 64) {
            const int cc = min(64, mc - base2);
            int s = 0; float w = 0.f;
            if (lane < cc) {
                s = adj[mb + base2 + lane];
                float tt = s_src[s] + sd;
                tt = (tt >= 0.f) ? tt : NEG_SLOPE * tt;
                w = __expf(tt - mx) * inv;
            }
            for (int jj = 0; jj < cc; jj += 8) {
                const int ja = jj + q;
                const int jb = ja + 4;
                float wa = __shfl(w, ja, 64); int sa = __shfl(s, ja, 64);
                float wb = __shfl(w, jb, 64); int sb = __shfl(s, jb, 64);
                wa = (ja < cc) ? wa : 0.f;
                wb = (jb < cc) ? wb : 0.f;
                uint4 za = *(const uint4*)&z[(size_t)sa * D + l16 * 8];
                uint4 zb = *(const uint4*)&z[(size_t)sb * D + l16 * 8];
                fma8(a, wa, za);
                fma8(bacc, wb, zb);
            }
        }
#pragma unroll
        for (int i = 0; i < 8; ++i) {
            a[i] += bacc[i];
            a[i] += __shfl_xor(a[i], 16, 64);
            a[i] += __shfl_xor(a[i], 32, 64);
        }
        if (q == 0) {
            float* o = &out[(size_t)myn * D + l16 * 8];
            *(float4*)o       = make_float4(a[0], a[1], a[2], a[3]);
            *(float4*)(o + 4) = make_float4(a[4], a[5], a[6], a[7]);
        }
    }
}

// ---------------- launch ----------------
extern "C" void kernel_launch(void* const* d_in, const int* in_sizes, int n_in,
                              void* d_out, int out_size, void* d_ws, size_t ws_size,
                              hipStream_t stream) {
    const float* h    = (const float*)d_in[0];
    const float* W    = (const float*)d_in[1];
    const float* aw   = (const float*)d_in[2];
    const int*   esrc = (const int*)d_in[3];
    const int*   edst = (const int*)d_in[4];
    float* out = (float*)d_out;

    const int N = in_sizes[0] / D;     // 100000
    const int E = in_sizes[3];         // 1600000
    const int NB1   = (N + 127) >> BSHIFT;     // fine blocks (782)
    const int NSORT = (E + SCHUNK - 1) / SCHUNK;
    const int NGEMM = (N + 63) / 64;           // gemm blocks (1563)

    char* p = (char*)d_ws;
    auto carve = [&](size_t bytes) {
        void* r = (void*)p;
        p += (bytes + 255) & ~size_t(255);
        return r;
    };
    unsigned short* z = (unsigned short*)carve(size_t(N) * D * sizeof(unsigned short));
    float* s_src  = (float*)carve(size_t(N) * sizeof(float));
    float* s_dst  = (float*)carve(size_t(N) * sizeof(float));
    int*   pairs  = (int*)carve(size_t(NB1) * SLOT * sizeof(int));
    int*   adj    = (int*)carve(size_t(NB1) * SLOT * sizeof(int));
    int*   beg    = (int*)carve(size_t(N) * sizeof(int));
    int*   ncnt   = (int*)carve(size_t(N) * sizeof(int));
    int*   gcur   = (int*)carve(size_t(B1) * sizeof(int));
    unsigned short* whi = (unsigned short*)carve(16384 * sizeof(unsigned short));
    unsigned short* wlo = (unsigned short*)carve(16384 * sizeof(unsigned short));
    (void)ws_size; (void)n_in; (void)out_size;

    hipMemsetAsync(gcur, 0, B1 * sizeof(int), stream);   // relative cursors
    sort_prep<<<NSORT + 16, 1024, 0, stream>>>(esrc, edst, gcur, pairs, E, NSORT,
                                               W, whi, wlo);
    fine_gemm<<<NB1 + NGEMM, 256, 0, stream>>>(pairs, gcur, beg, ncnt, adj, NB1,
                                               h, whi, wlo, aw, z, s_src, s_dst, N);
    aggregate<<<(N + 7) / 8, 256, 0, stream>>>(z, s_src, s_dst, beg, ncnt, adj, out, N);
}